// Round 6
// baseline (2902.329 us; speedup 1.0000x reference)
//
#include <hip/hip_runtime.h>
#include <hip/hip_bf16.h>

// LSTM T=512 B=256 NP=34 H=512 NT=16.
// R6 = R3-proven exchange protocol + in-register gate transpose.
// 16 groups (16 batches each) x 16 blocks (32 h-cols each, all 4 gates).
// W_hh|W_ih slice resident in LDS bf16, K = 512(h)+34(x)+pad = 576.
// Sync: NO flags/fences. hs pre-memset to 0xAAAAAAAA; every h dword written
// once (relaxed agent-scope store); consumers poll their own dwords until
// != sentinel — the successful poll IS the data load (R3-proven, 2128 us).
// New: D-col remap + 4x4 quartet XOR-transpose puts gates i,f,g,o in regs
// 0..3 per lane — no LDS gate exchange, 2 barriers/step instead of 4.
#define TT 512
#define BT 256
#define NP 34
#define HH 512
#define SENT 0xAAAAAAAAu

typedef short bf16x8 __attribute__((ext_vector_type(8)));
typedef float f32x4 __attribute__((ext_vector_type(4)));

static __device__ __forceinline__ unsigned short f2bf(float x) {
  unsigned int u = __float_as_uint(x);
  unsigned int r = (u + 0x7fffu + ((u >> 16) & 1u)) >> 16;
  return (unsigned short)r;
}

#define OKU64(x) (((unsigned int)(x) != SENT) && ((unsigned int)((x) >> 32) != SENT))

// LDS map (163840 B dynamic):
//   [0, 147456)        W slice bf16 [128 rows][576], 16B-chunk swizzle: phys_chunk = c ^ (r&7)
//   [147456, 163840)   hstage bf16 [16][512] (same swizzle)
__global__ void __launch_bounds__(256, 1) lstm_coop(
    const float* __restrict__ Whh, const float* __restrict__ Wih,
    const float* __restrict__ bih, const float* __restrict__ bhh,
    const unsigned short* __restrict__ Ax,  // [T][256][64] bf16 bits: [points(34), 0...]
    unsigned short* hs)                     // [T][256][512] bf16 bits, pre-set to SENT
{
  extern __shared__ char smem[];
  unsigned short* Wl = (unsigned short*)smem;
  unsigned short* hstage = (unsigned short*)(smem + 147456);

  const int tid = threadIdx.x;
  const int g = blockIdx.x & 15;   // group
  const int n = blockIdx.x >> 4;   // block-in-group -> h-cols [n*32, n*32+32)
  const int bbase = g * 16;        // batch base

  // ---- init resident W slice (swizzled) ----
  for (int idx = tid; idx < 128 * 576; idx += 256) {
    int r = idx / 576, k = idx - r * 576;
    int grow = (r >> 5) * 512 + n * 32 + (r & 31);  // gate q=r>>5 (i,f,g,o), hcol j=r&31
    float v = 0.f;
    if (k < 512) v = Whh[(size_t)grow * 512 + k];
    else if (k < 546) v = Wih[grow * 34 + (k - 512)];
    int c = k >> 3, within = k & 7;
    Wl[r * 576 + ((c ^ (r & 7)) << 3) + within] = f2bf(v);
  }

  const int lane = tid & 63;
  const int w = tid >> 6;
  const int m = lane & 15;   // A row (batch) / D col index
  const int ko = lane >> 4;
  const int qq = m & 3;      // quartet position = gate this lane accumulates
  const int js = m >> 2;
  // D-col -> W-row remap: col m=(4*js'+qq)... lane's B rows:
  //   acc0: rA = qq*32 + w*8 + 2*js (even col of pair), acc1: rB = rA+1.
  // Quartet lanes (same w,ko,js; qq=0..3) share col pair jc = w*8+2*js and
  // hold gates 0..3 -> 4x4 XOR transpose gives lane qq: regs 0..3 = gates
  // i,f,g,o for batch bloc = ko*4+qq at cols jc / jc+1.
  const int rA = qq * 32 + w * 8 + (js << 1);
  const int rB = rA + 1;
  const int pA = rA & 7, pB = rB & 7, pM = m & 7;
  const int bloc = ko * 4 + qq;
  const int jc = w * 8 + (js << 1);
  // bias for this lane's pre-transpose cols (gate qq, cols jc/jc+1)
  const int gbr = qq * 512 + n * 32 + jc;
  const float biasA = bih[gbr] + bhh[gbr];
  const float biasB = bih[gbr + 1] + bhh[gbr + 1];
  float c0s = 0.f, c1s = 0.f;

  for (int t = 0; t < TT; ++t) {
    // prefetch this step's x fragments (independent of h)
    const unsigned short* xbase = Ax + ((size_t)t * BT + bbase + m) * 64;
    bf16x8 xv0 = *(const bf16x8*)(xbase + (ko << 3));
    bf16x8 xv1 = *(const bf16x8*)(xbase + 32 + (ko << 3));

    // ---- acquire h(t-1): poll own 8 u64 units until non-sentinel (R3) ----
    unsigned long long hv[8];
    if (t > 0) {
      const unsigned long long* hb =
          (const unsigned long long*)(hs + ((size_t)(t - 1) * BT + bbase) * HH);
      unsigned int vm = 0;
      int guard = 0;
      while (vm != 0xffu) {
#pragma unroll
        for (int jj = 0; jj < 8; ++jj) {
          if (!((vm >> jj) & 1u)) {
            unsigned long long x = __hip_atomic_load(hb + jj * 256 + tid,
                                                     __ATOMIC_RELAXED,
                                                     __HIP_MEMORY_SCOPE_AGENT);
            if (OKU64(x)) { hv[jj] = x; vm |= (1u << jj); }
          }
        }
        if (vm == 0xffu) break;
        if (++guard > (1 << 20)) break;  // deadlock guard (wrong-answer, not hang)
        __builtin_amdgcn_s_sleep(1);
      }
    } else {
#pragma unroll
      for (int jj = 0; jj < 8; ++jj) hv[jj] = 0ull;
    }
    // stage into LDS (swizzled): u64 idx = jj*256+tid -> row mm, unit cu
#pragma unroll
    for (int jj = 0; jj < 8; ++jj) {
      int idx = jj * 256 + tid;
      int mm = idx >> 7, cu = idx & 127;
      int c16 = cu >> 1, half = cu & 1;
      *(unsigned long long*)&hstage[mm * 512 + ((c16 ^ (mm & 7)) << 3) + (half << 2)] = hv[jj];
    }
    __syncthreads();  // B1: hstage visible

    // ---- fused gates GEMM: [16 batch] x [128 gate rows], K=576 (h|x) ----
    f32x4 acc0 = {biasA, biasA, biasA, biasA};
    f32x4 acc1 = {biasB, biasB, biasB, biasB};
#pragma unroll
    for (int s = 0; s < 18; ++s) {
      int cc = 4 * s + ko;
      bf16x8 av;
      if (s < 16) {
        av = *(const bf16x8*)&hstage[m * 512 + ((cc ^ pM) << 3)];
      } else {
        av = (s == 16) ? xv0 : xv1;
      }
      bf16x8 bv0 = *(const bf16x8*)&Wl[rA * 576 + ((cc ^ pA) << 3)];
      bf16x8 bv1 = *(const bf16x8*)&Wl[rB * 576 + ((cc ^ pB) << 3)];
      acc0 = __builtin_amdgcn_mfma_f32_16x16x32_bf16(av, bv0, acc0, 0, 0, 0);
      acc1 = __builtin_amdgcn_mfma_f32_16x16x32_bf16(av, bv1, acc1, 0, 0, 0);
    }
    __syncthreads();  // B2: hstage reads done -> next-iter staging safe

    // ---- 4x4 quartet XOR transpose (lanes qq=0..3 within quartet) ----
    // Before: lane qq reg p = (gate qq, batch ko*4+p).
    // After : lane qq reg p = (gate p,  batch ko*4+qq).  [hand-verified table]
    float a, b;
#define TRQ(V, i0, i1, K, BIT)                       \
    a = (qq & BIT) ? V[i0] : V[i1];                  \
    b = __shfl_xor(a, K, 64);                        \
    if (qq & BIT) V[i0] = b; else V[i1] = b;
    TRQ(acc0, 0, 1, 1, 1) TRQ(acc0, 2, 3, 1, 1) TRQ(acc0, 0, 2, 2, 2) TRQ(acc0, 1, 3, 2, 2)
    TRQ(acc1, 0, 1, 1, 1) TRQ(acc1, 2, 3, 1, 1) TRQ(acc1, 0, 2, 2, 2) TRQ(acc1, 1, 3, 2, 2)
#undef TRQ

    // ---- epilogue: 2 adjacent cells (cols jc, jc+1) of batch bloc ----
    float i0 = 1.f / (1.f + __expf(-acc0[0])), i1 = 1.f / (1.f + __expf(-acc1[0]));
    float f0 = 1.f / (1.f + __expf(-acc0[1])), f1 = 1.f / (1.f + __expf(-acc1[1]));
    float g0 = 1.f - 2.f / (1.f + __expf(2.f * acc0[2]));
    float g1 = 1.f - 2.f / (1.f + __expf(2.f * acc1[2]));
    float o0 = 1.f / (1.f + __expf(-acc0[3])), o1 = 1.f / (1.f + __expf(-acc1[3]));
    c0s = f0 * c0s + i0 * g0;
    c1s = f1 * c1s + i1 * g1;
    float h0 = o0 * (1.f - 2.f / (1.f + __expf(2.f * c0s)));
    float h1 = o1 * (1.f - 2.f / (1.f + __expf(2.f * c1s)));
    unsigned int packed = (unsigned int)f2bf(h0) | ((unsigned int)f2bf(h1) << 16);
    // relaxed agent-scope store to coherent point; consumers self-validate
    // per dword, so no drain/release needed — fire and proceed. (R3-proven)
    __hip_atomic_store((unsigned int*)(hs + ((size_t)t * BT + bbase + bloc) * HH + n * 32 + jc),
                       packed, __ATOMIC_RELAXED, __HIP_MEMORY_SCOPE_AGENT);
  }
}

// Ax[t][b][k] = bf16(points[t][b][k]) for k<34 else 0
__global__ void __launch_bounds__(256) prep_ax(const float* __restrict__ pts,
                                               unsigned short* __restrict__ Ax) {
  size_t i = (size_t)blockIdx.x * 256 + threadIdx.x;  // [0, 512*256*64)
  int k = (int)(i & 63);
  size_t tb = i >> 6;
  float v = (k < NP) ? pts[tb * NP + k] : 0.f;
  Ax[i] = f2bf(v);
}

// logits = hs @ W_lin^T + b_lin ; softmax over 16
__global__ void __launch_bounds__(256) head_kernel(const unsigned short* __restrict__ hs,
                                                   const float* __restrict__ Wlin,
                                                   const float* __restrict__ blin,
                                                   float* __restrict__ out) {
  __shared__ float wl[16 * 513];
  __shared__ float bl[16];
  __shared__ unsigned short hl[16 * 520];
  const int tid = threadIdx.x;
  for (int i = tid; i < 16 * 512; i += 256) wl[(i >> 9) * 513 + (i & 511)] = Wlin[i];
  if (tid < 16) bl[tid] = blin[tid];
  const size_t Rb = (size_t)blockIdx.x * 16;  // 16 rows of [131072][512]
  const uint4* gsrc = (const uint4*)(hs + Rb * 512);
#pragma unroll
  for (int j = 0; j < 4; ++j) {
    int e8 = tid + 256 * j;  // uint4 index, 8 bf16 each
    uint4 v = gsrc[e8];
    int r = e8 >> 6, k = (e8 & 63) << 3;
    *(uint4*)&hl[r * 520 + k] = v;
  }
  __syncthreads();
  const int r = tid >> 4, tg = tid & 15;
  float acc = bl[tg];
  const float* wp = &wl[tg * 513];
#pragma unroll 4
  for (int k8 = 0; k8 < 64; ++k8) {
    uint4 hv = *(const uint4*)&hl[r * 520 + (k8 << 3)];
    const float* w8 = wp + (k8 << 3);
    acc += __uint_as_float(hv.x << 16) * w8[0];
    acc += __uint_as_float(hv.x & 0xffff0000u) * w8[1];
    acc += __uint_as_float(hv.y << 16) * w8[2];
    acc += __uint_as_float(hv.y & 0xffff0000u) * w8[3];
    acc += __uint_as_float(hv.z << 16) * w8[4];
    acc += __uint_as_float(hv.z & 0xffff0000u) * w8[5];
    acc += __uint_as_float(hv.w << 16) * w8[6];
    acc += __uint_as_float(hv.w & 0xffff0000u) * w8[7];
  }
  float mx = acc;
#pragma unroll
  for (int d = 8; d; d >>= 1) mx = fmaxf(mx, __shfl_xor(mx, d, 16));
  float e = __expf(acc - mx);
  float sm = e;
#pragma unroll
  for (int d = 8; d; d >>= 1) sm += __shfl_xor(sm, d, 16);
  out[Rb * 16 + tid] = e / sm;
}

extern "C" void kernel_launch(void* const* d_in, const int* in_sizes, int n_in,
                              void* d_out, int out_size, void* d_ws, size_t ws_size,
                              hipStream_t stream) {
  (void)in_sizes; (void)n_in; (void)out_size; (void)ws_size;
  const float* pts  = (const float*)d_in[0];
  const float* Wih  = (const float*)d_in[1];
  const float* Whh  = (const float*)d_in[2];
  const float* bih  = (const float*)d_in[3];
  const float* bhh  = (const float*)d_in[4];
  const float* Wlin = (const float*)d_in[5];
  const float* blin = (const float*)d_in[6];
  float* out = (float*)d_out;
  char* ws = (char*)d_ws;
  // ws layout: hs 134217728 B | Ax 16777216 B
  unsigned short* hs = (unsigned short*)ws;
  unsigned short* Ax = (unsigned short*)(ws + 134217728);

  hipMemsetAsync(hs, 0xAA, 134217728, stream);   // sentinel fill (every launch)
  prep_ax<<<32768, 256, 0, stream>>>(pts, Ax);
  (void)hipFuncSetAttribute((const void*)lstm_coop,
                            hipFuncAttributeMaxDynamicSharedMemorySize, 163840);
  void* args[6];
  args[0] = (void*)&Whh; args[1] = (void*)&Wih; args[2] = (void*)&bih;
  args[3] = (void*)&bhh; args[4] = (void*)&Ax;  args[5] = (void*)&hs;
  hipLaunchCooperativeKernel((void*)lstm_coop, dim3(256), dim3(256), args, 163840, stream);
  head_kernel<<<8192, 256, 0, stream>>>(hs, Wlin, blin, out);
}

// Round 7
// 2494.896 us; speedup vs baseline: 1.1633x; 1.1633x over previous
//
#include <hip/hip_runtime.h>
#include <hip/hip_bf16.h>

// LSTM T=512 B=256 NP=34 H=512 NT=16.
// R7: swapped-operand MFMA + canary-gated exchange.
// 16 groups (16 batches) x 16 blocks (32 h-cols, all 4 gates).
// - MFMA: A = W rows, B = h batches => D col = batch, D rows = W-rows.
//   LDS row pr = w*32 + e*16 + (4*jj+q) <-> (gate q, col w*8+2jj+e), so each
//   lane's acc regs 0..3 are gates i,f,g,o of one (batch, col) cell directly.
//   Addresses identical to R3's conflict-free pattern (swizzle c ^ (pr&7)).
// - Exchange: producer stores h (agent, relaxed) -> __syncthreads (vmcnt
//   drain = stores acked at L3) -> tid0 stores canary[t][g][n]. Consumers
//   poll ONLY the 16-canary line (16 lanes), then bulk-load 16 KB once
//   (sentinel-validated as safety net). Kills the L3 poll-traffic contention.
// - Epilogue: 1 KB LDS repack -> full-64B-line coalesced h stores (R3 shape).
#define TT 512
#define BT 256
#define NP 34
#define HH 512
#define SENT 0xAAAAAAAAu

typedef short bf16x8 __attribute__((ext_vector_type(8)));
typedef float f32x4 __attribute__((ext_vector_type(4)));

static __device__ __forceinline__ unsigned short f2bf(float x) {
  unsigned int u = __float_as_uint(x);
  unsigned int r = (u + 0x7fffu + ((u >> 16) & 1u)) >> 16;
  return (unsigned short)r;
}

#define OKU64(x) (((unsigned int)(x) != SENT) && ((unsigned int)((x) >> 32) != SENT))

// LDS map (163840 B dynamic):
//   [0, 147456)        Wl bf16 [128 rows][576], chunk swizzle: phys = c ^ (pr&7)
//   [147456, 163840)   hstage bf16 [16][512] (swizzled); first 1088 B aliased
//                      as hrep u32 [16 cp][17] during the store phase.
__global__ void __launch_bounds__(256, 1) lstm_coop(
    const float* __restrict__ Whh, const float* __restrict__ Wih,
    const float* __restrict__ bih, const float* __restrict__ bhh,
    const unsigned short* __restrict__ Ax,  // [T][256][64] bf16 bits
    unsigned short* hs,                     // [T][256][512] bf16 bits, pre-SENT
    unsigned int* can)                      // [T][16 g][16 n] canaries, pre-SENT
{
  extern __shared__ char smem[];
  unsigned short* Wl = (unsigned short*)smem;
  unsigned short* hstage = (unsigned short*)(smem + 147456);
  unsigned int* hrep = (unsigned int*)(smem + 147456);  // aliased

  const int tid = threadIdx.x;
  const int g = blockIdx.x & 15;   // group
  const int n = blockIdx.x >> 4;   // block-in-group -> h-cols [n*32, n*32+32)
  const int bbase = g * 16;        // batch base

  // ---- init resident W slice: pr = w*32 + e*16 + (4*jj+q) -> (gate q, col w*8+2jj+e)
  for (int idx = tid; idx < 128 * 576; idx += 256) {
    int pr = idx / 576, k = idx - pr * 576;
    int w_ = pr >> 5, e = (pr >> 4) & 1, mr = pr & 15;
    int jloc = w_ * 8 + ((mr >> 2) << 1) + e;           // col in [0,32)
    int grow = (mr & 3) * 512 + n * 32 + jloc;          // gate (mr&3), global col
    float v = 0.f;
    if (k < 512) v = Whh[(size_t)grow * 512 + k];
    else if (k < 546) v = Wih[grow * 34 + (k - 512)];
    int c = k >> 3, within = k & 7;
    Wl[pr * 576 + ((c ^ (pr & 7)) << 3) + within] = f2bf(v);
  }

  const int lane = tid & 63;
  const int w = tid >> 6;
  const int m = lane & 15;   // batch (B-operand col) AND A-fragment row low bits
  const int ko = lane >> 4;
  const int rA = 32 * w + m;        // A rows, e=0 tile (cols w*8+2*jj, jj=ko)
  const int rB = rA + 16;           // e=1 tile (odd cols)
  const int pM = m & 7;             // shared swizzle class (rA&7 == rB&7 == m&7)
  const int jc = w * 8 + (ko << 1); // local col of acc0; acc1 -> jc+1
  // acc reg p = gate p, so fold per-gate biases into acc init
  f32x4 biasA, biasB;
#pragma unroll
  for (int p = 0; p < 4; ++p) {
    int gr = p * 512 + n * 32 + jc;
    biasA[p] = bih[gr] + bhh[gr];
    biasB[p] = bih[gr + 1] + bhh[gr + 1];
  }
  float c0s = 0.f, c1s = 0.f;  // cell state for (batch m, cols jc, jc+1)

  for (int t = 0; t < TT; ++t) {
    // prefetch this step's x fragments (independent of h)
    const unsigned short* xbase = Ax + ((size_t)t * BT + bbase + m) * 64;
    bf16x8 xv0 = *(const bf16x8*)(xbase + (ko << 3));
    bf16x8 xv1 = *(const bf16x8*)(xbase + 32 + (ko << 3));

    unsigned long long hv[8];
    if (t > 0) {
      // ---- canary gate: 16 lanes poll one 64B line (low L3 traffic) ----
      if (tid < 16) {
        const unsigned int* cp_ = can + (size_t)(t - 1) * 256 + g * 16 + tid;
        int gu = 0;
        while (__hip_atomic_load(cp_, __ATOMIC_RELAXED, __HIP_MEMORY_SCOPE_AGENT) == SENT) {
          __builtin_amdgcn_s_sleep(1);
          if (++gu > (1 << 16)) break;  // bounded (wrong-answer, never hang)
        }
      }
      __syncthreads();  // B0: canaries seen -> producers' data acked at L3

      // ---- bulk load h(t-1): expected 1 round; sentinel-validated ----
      const unsigned long long* hb =
          (const unsigned long long*)(hs + ((size_t)(t - 1) * BT + bbase) * HH);
      unsigned int vm = 0;
      int guard = 0;
      while (vm != 0xffu) {
#pragma unroll
        for (int jj = 0; jj < 8; ++jj) {
          if (!((vm >> jj) & 1u)) {
            unsigned long long x = __hip_atomic_load(hb + jj * 256 + tid,
                                                     __ATOMIC_RELAXED,
                                                     __HIP_MEMORY_SCOPE_AGENT);
            if (OKU64(x)) { hv[jj] = x; vm |= (1u << jj); }
          }
        }
        if (vm == 0xffu) break;
        if (++guard > (1 << 14)) break;
        __builtin_amdgcn_s_sleep(1);
      }
    } else {
#pragma unroll
      for (int jj = 0; jj < 8; ++jj) hv[jj] = 0ull;
    }
    // stage into LDS (swizzled): u64 idx = jj*256+tid -> row mm, unit cu
#pragma unroll
    for (int jj = 0; jj < 8; ++jj) {
      int idx = jj * 256 + tid;
      int mm = idx >> 7, cu = idx & 127;
      int c16 = cu >> 1, half = cu & 1;
      *(unsigned long long*)&hstage[mm * 512 + ((c16 ^ (mm & 7)) << 3) + (half << 2)] = hv[jj];
    }
    __syncthreads();  // B1: hstage visible

    // ---- gates GEMM (swapped operands): D[Wrow][batch] ----
    f32x4 acc0 = biasA, acc1 = biasB;
#pragma unroll
    for (int s = 0; s < 18; ++s) {
      int cc = 4 * s + ko;
      int cs = (cc ^ pM) << 3;
      bf16x8 av;
      if (s < 16) {
        av = *(const bf16x8*)&hstage[m * 512 + cs];
      } else {
        av = (s == 16) ? xv0 : xv1;
      }
      bf16x8 bv0 = *(const bf16x8*)&Wl[rA * 576 + cs];
      bf16x8 bv1 = *(const bf16x8*)&Wl[rB * 576 + cs];
      acc0 = __builtin_amdgcn_mfma_f32_16x16x32_bf16(bv0, av, acc0, 0, 0, 0);
      acc1 = __builtin_amdgcn_mfma_f32_16x16x32_bf16(bv1, av, acc1, 0, 0, 0);
    }
    __syncthreads();  // B2: hstage reads done (hrep aliases it)

    // ---- epilogue: acc regs 0..3 = gates i,f,g,o for (batch m, col jc/jc+1)
    float i0 = 1.f / (1.f + __expf(-acc0[0])), i1 = 1.f / (1.f + __expf(-acc1[0]));
    float f0 = 1.f / (1.f + __expf(-acc0[1])), f1 = 1.f / (1.f + __expf(-acc1[1]));
    float g0 = 1.f - 2.f / (1.f + __expf(2.f * acc0[2]));
    float g1 = 1.f - 2.f / (1.f + __expf(2.f * acc1[2]));
    float o0 = 1.f / (1.f + __expf(-acc0[3])), o1 = 1.f / (1.f + __expf(-acc1[3]));
    c0s = f0 * c0s + i0 * g0;
    c1s = f1 * c1s + i1 * g1;
    float h0 = o0 * (1.f - 2.f / (1.f + __expf(2.f * c0s)));
    float h1 = o1 * (1.f - 2.f / (1.f + __expf(2.f * c1s)));
    unsigned int packed = (unsigned int)f2bf(h0) | ((unsigned int)f2bf(h1) << 16);
    hrep[(w * 4 + ko) * 17 + m] = packed;  // [col-pair][batch], +1 pad
    __syncthreads();  // B3: hrep visible

    // ---- coalesced store: thread tid -> (batch tid>>4, col-pair tid&15) ----
    unsigned int val = hrep[(tid & 15) * 17 + (tid >> 4)];
    unsigned int* dst = (unsigned int*)hs +
        ((size_t)t * BT + bbase + (tid >> 4)) * 256 + n * 16 + (tid & 15);
    __hip_atomic_store(dst, val, __ATOMIC_RELAXED, __HIP_MEMORY_SCOPE_AGENT);
    __syncthreads();  // B4: drains stores (acked at L3); hrep reads done
    if (tid == 0) {
      __hip_atomic_store(can + (size_t)t * 256 + g * 16 + n, 1u,
                         __ATOMIC_RELAXED, __HIP_MEMORY_SCOPE_AGENT);
    }
  }
}

// Ax[t][b][k] = bf16(points[t][b][k]) for k<34 else 0
__global__ void __launch_bounds__(256) prep_ax(const float* __restrict__ pts,
                                               unsigned short* __restrict__ Ax) {
  size_t i = (size_t)blockIdx.x * 256 + threadIdx.x;  // [0, 512*256*64)
  int k = (int)(i & 63);
  size_t tb = i >> 6;
  float v = (k < NP) ? pts[tb * NP + k] : 0.f;
  Ax[i] = f2bf(v);
}

// logits = hs @ W_lin^T + b_lin ; softmax over 16
__global__ void __launch_bounds__(256) head_kernel(const unsigned short* __restrict__ hs,
                                                   const float* __restrict__ Wlin,
                                                   const float* __restrict__ blin,
                                                   float* __restrict__ out) {
  __shared__ float wl[16 * 513];
  __shared__ float bl[16];
  __shared__ unsigned short hl[16 * 520];
  const int tid = threadIdx.x;
  for (int i = tid; i < 16 * 512; i += 256) wl[(i >> 9) * 513 + (i & 511)] = Wlin[i];
  if (tid < 16) bl[tid] = blin[tid];
  const size_t Rb = (size_t)blockIdx.x * 16;  // 16 rows of [131072][512]
  const uint4* gsrc = (const uint4*)(hs + Rb * 512);
#pragma unroll
  for (int j = 0; j < 4; ++j) {
    int e8 = tid + 256 * j;  // uint4 index, 8 bf16 each
    uint4 v = gsrc[e8];
    int r = e8 >> 6, k = (e8 & 63) << 3;
    *(uint4*)&hl[r * 520 + k] = v;
  }
  __syncthreads();
  const int r = tid >> 4, tg = tid & 15;
  float acc = bl[tg];
  const float* wp = &wl[tg * 513];
#pragma unroll 4
  for (int k8 = 0; k8 < 64; ++k8) {
    uint4 hv = *(const uint4*)&hl[r * 520 + (k8 << 3)];
    const float* w8 = wp + (k8 << 3);
    acc += __uint_as_float(hv.x << 16) * w8[0];
    acc += __uint_as_float(hv.x & 0xffff0000u) * w8[1];
    acc += __uint_as_float(hv.y << 16) * w8[2];
    acc += __uint_as_float(hv.y & 0xffff0000u) * w8[3];
    acc += __uint_as_float(hv.z << 16) * w8[4];
    acc += __uint_as_float(hv.z & 0xffff0000u) * w8[5];
    acc += __uint_as_float(hv.w << 16) * w8[6];
    acc += __uint_as_float(hv.w & 0xffff0000u) * w8[7];
  }
  float mx = acc;
#pragma unroll
  for (int d = 8; d; d >>= 1) mx = fmaxf(mx, __shfl_xor(mx, d, 16));
  float e = __expf(acc - mx);
  float sm = e;
#pragma unroll
  for (int d = 8; d; d >>= 1) sm += __shfl_xor(sm, d, 16);
  out[Rb * 16 + tid] = e / sm;
}

extern "C" void kernel_launch(void* const* d_in, const int* in_sizes, int n_in,
                              void* d_out, int out_size, void* d_ws, size_t ws_size,
                              hipStream_t stream) {
  (void)in_sizes; (void)n_in; (void)out_size; (void)ws_size;
  const float* pts  = (const float*)d_in[0];
  const float* Wih  = (const float*)d_in[1];
  const float* Whh  = (const float*)d_in[2];
  const float* bih  = (const float*)d_in[3];
  const float* bhh  = (const float*)d_in[4];
  const float* Wlin = (const float*)d_in[5];
  const float* blin = (const float*)d_in[6];
  float* out = (float*)d_out;
  char* ws = (char*)d_ws;
  // ws layout: hs 134217728 B | Ax 16777216 B | can 524288 B
  unsigned short* hs = (unsigned short*)ws;
  unsigned short* Ax = (unsigned short*)(ws + 134217728);
  unsigned int* can  = (unsigned int*)(ws + 150994944);

  hipMemsetAsync(hs, 0xAA, 134217728, stream);   // sentinel fill (every launch)
  hipMemsetAsync(can, 0xAA, 524288, stream);
  prep_ax<<<32768, 256, 0, stream>>>(pts, Ax);
  (void)hipFuncSetAttribute((const void*)lstm_coop,
                            hipFuncAttributeMaxDynamicSharedMemorySize, 163840);
  void* args[7];
  args[0] = (void*)&Whh; args[1] = (void*)&Wih; args[2] = (void*)&bih;
  args[3] = (void*)&bhh; args[4] = (void*)&Ax;  args[5] = (void*)&hs;
  args[6] = (void*)&can;
  hipLaunchCooperativeKernel((void*)lstm_coop, dim3(256), dim3(256), args, 163840, stream);
  head_kernel<<<8192, 256, 0, stream>>>(hs, Wlin, blin, out);
}